// Round 9
// baseline (182.375 us; speedup 1.0000x reference)
//
#include <hip/hip_runtime.h>

// Problem constants (match reference setup_inputs)
#define BB 16
#define SS 2048
#define DD 768
#define RB 8                   // rows per tile (8 x 3072B = 24KB per LDS buffer)
#define RW 2                   // rows per wave per tile (4 waves)
#define TPB 4                  // consecutive tiles per block
#define NTILE (BB * SS / RB)   // 4096
#define NBLK (NTILE / TPB)     // 1024

#define ADD4(A, R) { A.x += R.x; A.y += R.y; A.z += R.z; A.w += R.w; }

// Async global->LDS, 16B/lane, wave-uniform LDS base (+lane*16 implicit).
// aux=2 = NT read policy (x is read-once).
#define GLOAD_LDS16_NT(gaddr, laddr)                                           \
    __builtin_amdgcn_global_load_lds(                                          \
        (const __attribute__((address_space(1))) void*)(gaddr),                \
        (__attribute__((address_space(3))) void*)(laddr), 16, 0, 2)

// Write one output row (mean of c rows) + zero-fill the gap up to vnext.
__device__ __forceinline__ void emit_row(float* __restrict__ ob, int v, int vnext,
                                         int c, float4 a0, float4 a1, float4 a2,
                                         int lane) {
    float inv = 1.0f / (float)c;
    a0.x *= inv; a0.y *= inv; a0.z *= inv; a0.w *= inv;
    a1.x *= inv; a1.y *= inv; a1.z *= inv; a1.w *= inv;
    a2.x *= inv; a2.y *= inv; a2.z *= inv; a2.w *= inv;
    float4* op = (float4*)(ob + (size_t)v * DD);
    op[lane]       = a0;
    op[lane + 64]  = a1;
    op[lane + 128] = a2;
    const float4 zz = make_float4(0.f, 0.f, 0.f, 0.f);
    for (int z = v + 1; z < vnext; ++z) {
        float4* zp = (float4*)(ob + (size_t)z * DD);
        zp[lane] = zz; zp[lane + 64] = zz; zp[lane + 128] = zz;
    }
}

// v8: double-buffered LDS pipeline with COUNTED vmcnt (T3/T4-minimum).
// v5/v6 post-mortem: __syncthreads() drains vmcnt(0) — each block fully
// stalls on its 48KB stage with only ~1.7 blocks/CU resident to cover it
// (burst->drain->compute duty cycle => 2.4 of 6.3 TB/s). Here each block
// walks 4 consecutive 8-row tiles; next tile's loads are issued BEFORE the
// barrier and only the CURRENT tile is waited on (s_waitcnt vmcnt(6)), so
// every wave keeps ~6KB of reads in flight continuously (~72KB/CU).
__global__ __launch_bounds__(256) void seg_mean_v8(
    const float* __restrict__ x,
    const int*   __restrict__ seg,
    float*       __restrict__ out) {
    __shared__ float lds[2][RB * DD];          // 2 x 24576 B
    int lane = threadIdx.x & 63;
    int wv   = threadIdx.x >> 6;
    int g0   = blockIdx.x * TPB;               // first tile of this block

    // ---- Prologue: stage tile g0 into buf 0 ----
    {
        const float* gsrc = x + (size_t)g0 * (RB * DD) + (wv * RW) * DD + lane * 4;
        float*       ldst = &lds[0][(wv * RW) * DD];
        #pragma unroll
        for (int k = 0; k < RW * 3; ++k)       // 6 x 1024B per wave
            GLOAD_LDS16_NT(gsrc + k * 256, ldst + k * 256);
    }

    #pragma unroll
    for (int t = 0; t < TPB; ++t) {
        int g  = g0 + t;
        int p0 = g * RB;                       // first input position of tile
        int b  = p0 >> 11;                     // / SS (RB | SS: no row crossing)
        int q0 = p0 & (SS - 1);

        // ---- Stage NEXT tile, then wait only for CURRENT tile's loads ----
        if (t + 1 < TPB) {
            const float* gsrc = x + (size_t)(g + 1) * (RB * DD) + (wv * RW) * DD + lane * 4;
            float*       ldst = &lds[(t + 1) & 1][(wv * RW) * DD];
            #pragma unroll
            for (int k = 0; k < RW * 3; ++k)
                GLOAD_LDS16_NT(gsrc + k * 256, ldst + k * 256);
            asm volatile("s_waitcnt vmcnt(6)" ::: "memory");  // keep 6 newest in flight
        } else {
            asm volatile("s_waitcnt vmcnt(0)" ::: "memory");
        }
        asm volatile("s_barrier" ::: "memory"); // all waves' current-tile loads done

        const float* buf  = lds[t & 1];
        const int*   srow = seg + (b << 11);
        const float* xb   = x   + (size_t)(b << 11) * DD;
        float*       ob   = out + (size_t)(b << 11) * DD;

        // ---- Run-start detection over the tile's RB positions ----
        int  myv = 0;
        bool startl = false;
        if (lane < RB) {
            int p = q0 + lane;
            myv = srow[p];
            int pv = (p == 0) ? (myv ^ 1) : srow[p - 1];  // force start at p==0
            startl = (myv != pv);
        }
        unsigned long long smask = __ballot(startl);      // bits 0..RB-1

        // Head gap: tile at q0==0, wave 0 zero-fills slots [0, srow[0])
        if (q0 == 0 && wv == 0) {
            int first = srow[0];
            const float4 zz = make_float4(0.f, 0.f, 0.f, 0.f);
            for (int z = 0; z < first; ++z) {
                float4* zp = (float4*)(ob + (size_t)z * DD);
                zp[lane] = zz; zp[lane + 64] = zz; zp[lane + 128] = zz;
            }
        }

        // ---- Wave wv owns runs starting in rows [wv*RW, wv*RW+RW) ----
        unsigned wmask = (unsigned)(smask >> (wv * RW)) & ((1u << RW) - 1);
        while (wmask) {
            int jrel = __builtin_ctz(wmask); wmask &= wmask - 1;
            int j    = wv * RW + jrel;         // tile-local run start
            int vcur = __shfl(myv, j);

            unsigned long long above = smask >> (j + 1);
            int  e_loc;
            bool tail;
            if (above) { e_loc = j + 1 + (int)__builtin_ctzll(above); tail = false; }
            else       { e_loc = RB;                                  tail = true;  }

            // Sum rows [j, e_loc) from LDS
            const float4* lp = (const float4*)(buf + (size_t)j * DD);
            float4 a0 = lp[lane], a1 = lp[lane + 64], a2 = lp[lane + 128];
            for (int r = j + 1; r < e_loc; ++r) {
                const float4* q = (const float4*)(buf + (size_t)r * DD);
                float4 r0 = q[lane], r1 = q[lane + 64], r2 = q[lane + 128];
                ADD4(a0, r0); ADD4(a1, r1); ADD4(a2, r2);
            }

            int c, vnext;
            if (!tail) {
                c     = e_loc - j;
                vnext = __shfl(myv, e_loc);
            } else {
                // Run may extend past the tile: scan seg, sum extras from global
                int e = q0 + RB;
                if (e < SS) {
                    for (;;) {
                        int idx = e + lane;
                        int vv  = (idx < SS) ? srow[idx] : (vcur ^ 1);  // OOB != vcur
                        unsigned long long m  = __ballot(vv == vcur);
                        unsigned long long nm = ~m;
                        if (nm) { e += (int)__builtin_ctzll(nm); break; }
                        e += 64;
                    }
                }
                for (int r = q0 + RB; r < e; ++r) {
                    const float4* xn = (const float4*)(xb + (size_t)r * DD);
                    float4 r0 = xn[lane], r1 = xn[lane + 64], r2 = xn[lane + 128];
                    ADD4(a0, r0); ADD4(a1, r1); ADD4(a2, r2);
                }
                c     = e - (q0 + j);
                vnext = (e < SS) ? srow[e] : SS;
            }
            emit_row(ob, vcur, vnext, c, a0, a1, a2, lane);
        }

        // Protect buf[t&1] before it is restaged next iteration
        asm volatile("s_barrier" ::: "memory");
    }
}

extern "C" void kernel_launch(void* const* d_in, const int* in_sizes, int n_in,
                              void* d_out, int out_size, void* d_ws, size_t ws_size,
                              hipStream_t stream) {
    const float* x   = (const float*)d_in[0];   // [B,S,D] fp32
    const int*   seg = (const int*)d_in[1];     // [B,S] int32
    float* out = (float*)d_out;                 // [B,S,D] fp32

    seg_mean_v8<<<NBLK, 256, 0, stream>>>(x, seg, out);  // 1024 blocks
}

// Round 10
// 176.380 us; speedup vs baseline: 1.0340x; 1.0340x over previous
//
#include <hip/hip_runtime.h>

// Problem constants (match reference setup_inputs)
#define BB 16
#define SS 2048
#define DD 768
#define D4 (DD / 4)   // 192 float4 per row
#define RB 16         // rows per block (16 x 3072B = 48KB LDS tile)
#define RW 4          // rows per wave (RB / 4 waves)

#define ADD4(A, R) { A.x += R.x; A.y += R.y; A.z += R.z; A.w += R.w; }

// Async global->LDS, 16B per lane, wave-uniform LDS base + lane*16.
// aux=2 sets the NT (non-temporal) cache-policy bit (gfx940+ CPol): x is
// read-once, so don't let it allocate/displace in L2/L3.
#define GLOAD_LDS16_NT(gaddr, laddr)                                           \
    __builtin_amdgcn_global_load_lds(                                          \
        (const __attribute__((address_space(1))) void*)(gaddr),                \
        (__attribute__((address_space(3))) void*)(laddr), 16, 0, 2)

// Write one output row (mean of c rows) + zero-fill the gap up to vnext.
__device__ __forceinline__ void emit_row(float* __restrict__ ob, int v, int vnext,
                                         int c, float4 a0, float4 a1, float4 a2,
                                         int lane) {
    float inv = 1.0f / (float)c;
    a0.x *= inv; a0.y *= inv; a0.z *= inv; a0.w *= inv;
    a1.x *= inv; a1.y *= inv; a1.z *= inv; a1.w *= inv;
    a2.x *= inv; a2.y *= inv; a2.z *= inv; a2.w *= inv;
    float4* op = (float4*)(ob + (size_t)v * DD);
    op[lane]       = a0;
    op[lane + 64]  = a1;
    op[lane + 128] = a2;
    const float4 zz = make_float4(0.f, 0.f, 0.f, 0.f);
    for (int z = v + 1; z < vnext; ++z) {
        float4* zp = (float4*)(ob + (size_t)z * DD);
        zp[lane] = zz; zp[lane + 64] = zz; zp[lane + 128] = zz;
    }
}

// FINAL (revert to v6, the best measured variant: harness 175.99 us).
// Session ledger: seven structurally disjoint formulations (gather /
// cooperative search / stream / reg-preload / async-LDS burst / two-pass /
// counted-vmcnt double-buffer) all land at 60-67 us kernel time with
// byte-identical HBM traffic (FETCH ~51 MB, WRITE ~98 MB, ~2.4 TB/s mixed).
// Logical traffic is already minimal (read x once — half L3-served — write
// out once). The mixed read+write service rate for this dispatch is the
// empirical plateau; no software structure tested moves it.
__global__ __launch_bounds__(256) void seg_mean_v6(
    const float* __restrict__ x,
    const int*   __restrict__ seg,
    float*       __restrict__ out) {
    __shared__ float lds[RB * DD];             // 49152 B
    int lane = threadIdx.x & 63;
    int wv   = threadIdx.x >> 6;
    int p0   = blockIdx.x * RB;                // global first position
    int b    = p0 >> 11;                       // / SS  (blocks never cross rows)
    int q0   = p0 & (SS - 1);                  // position within batch row
    const int*   srow = seg + (b << 11);
    const float* xb   = x   + (size_t)(b << 11) * DD;
    float*       ob   = out + (size_t)(b << 11) * DD;

    // ---- LOAD PHASE: wave wv stages rows [wv*RW, wv*RW+RW) into LDS ----
    {
        const float* gsrc = xb + (size_t)(q0 + wv * RW) * DD + lane * 4;
        float*       ldst = lds + (wv * RW) * DD;
        #pragma unroll
        for (int k = 0; k < RW * 3; ++k) {     // 12 x 1024B per wave
            GLOAD_LDS16_NT(gsrc + k * 256, ldst + k * 256);
        }
    }

    // ---- Run-start detection over the block's RB positions (overlaps loads)
    int  myv = 0;
    bool startl = false;
    if (lane < RB) {
        int p = q0 + lane;
        myv = srow[p];
        int pv = (p == 0) ? (myv ^ 1) : srow[p - 1];  // force start at p==0
        startl = (myv != pv);
    }
    unsigned long long smask = __ballot(startl);      // bits 0..RB-1

    // Head gap: block at q0==0, wave 0 zero-fills slots [0, srow[0])
    if (q0 == 0 && wv == 0) {
        int first = srow[0];
        const float4 zz = make_float4(0.f, 0.f, 0.f, 0.f);
        for (int z = 0; z < first; ++z) {
            float4* zp = (float4*)(ob + (size_t)z * DD);
            zp[lane] = zz; zp[lane + 64] = zz; zp[lane + 128] = zz;
        }
    }

    __syncthreads();                           // vmcnt(0): LDS tile ready

    // ---- COMPUTE PHASE: wave wv owns runs starting in [wv*RW, wv*RW+RW) ----
    unsigned wmask = (unsigned)(smask >> (wv * RW)) & ((1u << RW) - 1);
    while (wmask) {
        int jrel = __builtin_ctz(wmask); wmask &= wmask - 1;
        int j    = wv * RW + jrel;             // block-local run start
        int vcur = __shfl(myv, j);

        unsigned long long above = smask >> (j + 1);
        int  e_loc;
        bool tail;
        if (above) { e_loc = j + 1 + (int)__builtin_ctzll(above); tail = false; }
        else       { e_loc = RB;                                  tail = true;  }

        // Sum rows [j, e_loc) from LDS
        const float4* lp = (const float4*)(lds + (size_t)j * DD);
        float4 a0 = lp[lane], a1 = lp[lane + 64], a2 = lp[lane + 128];
        for (int t = j + 1; t < e_loc; ++t) {
            const float4* q = (const float4*)(lds + (size_t)t * DD);
            float4 r0 = q[lane], r1 = q[lane + 64], r2 = q[lane + 128];
            ADD4(a0, r0); ADD4(a1, r1); ADD4(a2, r2);
        }

        int c, vnext;
        if (!tail) {
            c     = e_loc - j;
            vnext = __shfl(myv, e_loc);
        } else {
            // Run may extend past the tile: scan seg, sum extra rows from global
            int e = q0 + RB;
            if (e < SS) {
                for (;;) {
                    int idx = e + lane;
                    int vv  = (idx < SS) ? srow[idx] : (vcur ^ 1);  // OOB != vcur
                    unsigned long long m  = __ballot(vv == vcur);
                    unsigned long long nm = ~m;
                    if (nm) { e += (int)__builtin_ctzll(nm); break; }
                    e += 64;
                }
            }
            for (int t = q0 + RB; t < e; ++t) {
                const float4* xn = (const float4*)(xb + (size_t)t * DD);
                float4 r0 = xn[lane], r1 = xn[lane + 64], r2 = xn[lane + 128];
                ADD4(a0, r0); ADD4(a1, r1); ADD4(a2, r2);
            }
            c     = e - (q0 + j);
            vnext = (e < SS) ? srow[e] : SS;
        }
        emit_row(ob, vcur, vnext, c, a0, a1, a2, lane);
    }
}

extern "C" void kernel_launch(void* const* d_in, const int* in_sizes, int n_in,
                              void* d_out, int out_size, void* d_ws, size_t ws_size,
                              hipStream_t stream) {
    const float* x   = (const float*)d_in[0];   // [B,S,D] fp32
    const int*   seg = (const int*)d_in[1];     // [B,S] int32
    float* out = (float*)d_out;                 // [B,S,D] fp32

    int nBlocks = (BB * SS) / RB;               // 2048
    seg_mean_v6<<<nBlocks, 256, 0, stream>>>(x, seg, out);
}